// Round 1
// baseline (228.379 us; speedup 1.0000x reference)
//
#include <hip/hip_runtime.h>

#define HW_H 64
#define HW_W 64
#define NBATCH 4
#define C_IN 256
#define NG 8
#define NC 32
#define NK 9
#define NPIX (NBATCH * HW_H * HW_W)   // 16384

// ---------------------------------------------------------------------------
// Generic fp32 GEMM: Y[N][Ncols] = X[N][256] @ W[256][Ncols] (+ bias)
// Tile: 64 rows x 64 cols, BK=32. 256 threads, each computes 4x4 outputs.
// xs stored k-major transposed with stride 68 (16B-aligned rows, bank-spread),
// ws stored [32][64]. Both read via float4 -> conflict-free / 2-way.
// ---------------------------------------------------------------------------
__global__ __launch_bounds__(256) void gemm_f32_kernel(
    const float* __restrict__ X, const float* __restrict__ W,
    const float* __restrict__ bias, float* __restrict__ Y, int Ncols)
{
    __shared__ float xs[32][68];  // [k][m], stride 68 floats = 272B (16B aligned)
    __shared__ float ws[32][64];  // [k][n]

    const int tid  = threadIdx.x;
    const int row0 = blockIdx.x * 64;
    const int col0 = blockIdx.y * 64;
    const int ty   = tid >> 4;   // 0..15 -> row group
    const int tx   = tid & 15;   // 0..15 -> col group

    float acc[4][4] = {};

    for (int k0 = 0; k0 < C_IN; k0 += 32) {
        // Stage X tile (64 rows x 32 k) as float4, store transposed
        #pragma unroll
        for (int i = 0; i < 2; ++i) {
            int idx = tid + i * 256;          // 0..511
            int r   = idx >> 3;               // 0..63
            int kc  = (idx & 7) << 2;         // 0,4,..,28
            const float4 v = *(const float4*)(X + (size_t)(row0 + r) * C_IN + k0 + kc);
            xs[kc + 0][r] = v.x;
            xs[kc + 1][r] = v.y;
            xs[kc + 2][r] = v.z;
            xs[kc + 3][r] = v.w;
        }
        // Stage W tile (32 k x 64 n), zero-fill out-of-range cols
        #pragma unroll
        for (int i = 0; i < 8; ++i) {
            int idx = tid + i * 256;          // 0..2047
            int kk  = idx >> 6;               // 0..31
            int n   = idx & 63;
            int col = col0 + n;
            ws[kk][n] = (col < Ncols) ? W[(size_t)(k0 + kk) * Ncols + col] : 0.f;
        }
        __syncthreads();

        #pragma unroll
        for (int kk = 0; kk < 32; ++kk) {
            const float4 a4 = *(const float4*)&xs[kk][ty * 4];
            const float4 b4 = *(const float4*)&ws[kk][tx * 4];
            const float a[4] = {a4.x, a4.y, a4.z, a4.w};
            const float b[4] = {b4.x, b4.y, b4.z, b4.w};
            #pragma unroll
            for (int i = 0; i < 4; ++i)
                #pragma unroll
                for (int j = 0; j < 4; ++j)
                    acc[i][j] = fmaf(a[i], b[j], acc[i][j]);
        }
        __syncthreads();
    }

    // Epilogue
    #pragma unroll
    for (int i = 0; i < 4; ++i) {
        const int row = row0 + ty * 4 + i;
        #pragma unroll
        for (int j = 0; j < 4; ++j) {
            const int col = col0 + tx * 4 + j;
            if (col < Ncols) {
                float r = acc[i][j];
                if (bias) r += bias[col];
                Y[(size_t)row * Ncols + col] = r;
            }
        }
    }
}

// ---------------------------------------------------------------------------
// Deformable sampling: one block per pixel; thread = (group g, channel c).
// mid[pix][g][c] = sum_k w[g][k] * bilinear(v, pos[g][k])[c]
// ---------------------------------------------------------------------------
__device__ __forceinline__ float dcn_tap(const float* __restrict__ vb, int y, int x)
{
    const bool valid = (y >= 0) & (y < HW_H) & (x >= 0) & (x < HW_W);
    const int yc = min(max(y, 0), HW_H - 1);
    const int xc = min(max(x, 0), HW_W - 1);
    const float val = vb[((size_t)yc * HW_W + xc) * (NG * NC)];
    return valid ? val : 0.f;
}

__global__ __launch_bounds__(256) void dcn_sample_kernel(
    const float* __restrict__ v_buf,   // [N][G*C]
    const float* __restrict__ qd_buf,  // [N][G*K*2]
    const float* __restrict__ qs_buf,  // [N][G*K]
    const float* __restrict__ qw_buf,  // [N][G*K]
    const float* __restrict__ prior,   // [K][2]
    const float* __restrict__ dscale,  // [G]
    float* __restrict__ mid)           // [N][G*C]
{
    const int pix = blockIdx.x;
    const int g   = threadIdx.x >> 5;  // 0..7
    const int c   = threadIdx.x & 31;  // 0..31

    const int b  = pix / (HW_H * HW_W);
    const int hw = pix % (HW_H * HW_W);
    const int h  = hw / HW_W;
    const int w  = hw % HW_W;

    const float ds = dscale[g];
    const float* vb = v_buf + (size_t)b * (HW_H * HW_W * NG * NC) + g * NC + c;
    const float* qd = qd_buf + (size_t)pix * (NG * NK * 2) + g * (NK * 2);
    const float* qs = qs_buf + (size_t)pix * (NG * NK) + g * NK;
    const float* qw = qw_buf + (size_t)pix * (NG * NK) + g * NK;

    float acc = 0.f;
    #pragma unroll
    for (int k = 0; k < NK; ++k) {
        const float qdx = qd[k * 2 + 0];
        const float qdy = qd[k * 2 + 1];
        const float s   = qs[k] + ds;
        const float sig6 = 6.0f / (1.f + __expf(-s));
        const float px = fmaf(qdx + prior[k * 2 + 0], sig6, (float)w);
        const float py = fmaf(qdy + prior[k * 2 + 1], sig6, (float)h);
        const float wt = qw[k];

        const float x0f = floorf(px);
        const float y0f = floorf(py);
        const int ix = (int)x0f;
        const int iy = (int)y0f;
        const float wx1 = px - x0f, wx0 = 1.f - wx1;
        const float wy1 = py - y0f, wy0 = 1.f - wy1;

        const float v00 = dcn_tap(vb, iy,     ix);
        const float v01 = dcn_tap(vb, iy,     ix + 1);
        const float v10 = dcn_tap(vb, iy + 1, ix);
        const float v11 = dcn_tap(vb, iy + 1, ix + 1);

        const float bil = wy0 * fmaf(wx0, v00, wx1 * v01)
                        + wy1 * fmaf(wx0, v10, wx1 * v11);
        acc = fmaf(wt, bil, acc);
    }
    mid[(size_t)pix * (NG * NC) + g * NC + c] = acc;
}

// ---------------------------------------------------------------------------
extern "C" void kernel_launch(void* const* d_in, const int* in_sizes, int n_in,
                              void* d_out, int out_size, void* d_ws, size_t ws_size,
                              hipStream_t stream)
{
    (void)in_sizes; (void)n_in; (void)out_size; (void)ws_size;

    const float* x     = (const float*)d_in[0];
    const float* v_w   = (const float*)d_in[1];
    const float* v_b   = (const float*)d_in[2];
    const float* qd_w  = (const float*)d_in[3];
    const float* qd_b  = (const float*)d_in[4];
    const float* qs_w  = (const float*)d_in[5];
    const float* qw_w  = (const float*)d_in[6];
    const float* qw_b  = (const float*)d_in[7];
    const float* out_w = (const float*)d_in[8];
    const float* out_b = (const float*)d_in[9];
    const float* prior = (const float*)d_in[10];
    const float* dscale= (const float*)d_in[11];
    float* out = (float*)d_out;

    float* v_buf  = (float*)d_ws;                       // N*256
    float* qd_buf = v_buf  + (size_t)NPIX * 256;        // N*144
    float* qs_buf = qd_buf + (size_t)NPIX * 144;        // N*72
    float* qw_buf = qs_buf + (size_t)NPIX * 72;         // N*72
    float* mid    = qw_buf + (size_t)NPIX * 72;         // N*256

    const dim3 blk(256);

    gemm_f32_kernel<<<dim3(NPIX / 64, 4), blk, 0, stream>>>(x, v_w,  v_b,   v_buf,  256);
    gemm_f32_kernel<<<dim3(NPIX / 64, 3), blk, 0, stream>>>(x, qd_w, qd_b,  qd_buf, 144);
    gemm_f32_kernel<<<dim3(NPIX / 64, 2), blk, 0, stream>>>(x, qs_w, nullptr, qs_buf, 72);
    gemm_f32_kernel<<<dim3(NPIX / 64, 2), blk, 0, stream>>>(x, qw_w, qw_b,  qw_buf, 72);

    dcn_sample_kernel<<<dim3(NPIX), blk, 0, stream>>>(v_buf, qd_buf, qs_buf, qw_buf,
                                                      prior, dscale, mid);

    gemm_f32_kernel<<<dim3(NPIX / 64, 4), blk, 0, stream>>>(mid, out_w, out_b, out, 256);
}

// Round 2
// 61.249 us; speedup vs baseline: 3.7287x; 3.7287x over previous
//
#include <hip/hip_runtime.h>

#define NPIX 16384

typedef __attribute__((ext_vector_type(8))) short short8;
typedef __attribute__((ext_vector_type(4))) float f32x4;

__device__ __forceinline__ unsigned short f2bf(float f) {
    unsigned u = __float_as_uint(f);
    unsigned r = (u + 0x7fffu + ((u >> 16) & 1u)) >> 16;
    return (unsigned short)r;
}

#define GLOAD16(SRC, DST) \
    __builtin_amdgcn_global_load_lds( \
        (const __attribute__((address_space(1))) unsigned*)(SRC), \
        (__attribute__((address_space(3))) unsigned*)(DST), 16, 0, 0)

// ---------------------------------------------------------------------------
// prep_x: x f32 [16384][256] -> bf16, 8 elems/thread, grid 2048 x 256
// ---------------------------------------------------------------------------
__global__ __launch_bounds__(256) void prep_x(const float* __restrict__ x,
                                              unsigned short* __restrict__ xb)
{
    const size_t i = (size_t)blockIdx.x * 256 + threadIdx.x;
    const float4 v0 = *(const float4*)(x + i * 8);
    const float4 v1 = *(const float4*)(x + i * 8 + 4);
    unsigned r0 = f2bf(v0.x) | ((unsigned)f2bf(v0.y) << 16);
    unsigned r1 = f2bf(v0.z) | ((unsigned)f2bf(v0.w) << 16);
    unsigned r2 = f2bf(v1.x) | ((unsigned)f2bf(v1.y) << 16);
    unsigned r3 = f2bf(v1.z) | ((unsigned)f2bf(v1.w) << 16);
    *(uint4*)(xb + i * 8) = make_uint4(r0, r1, r2, r3);
}

// ---------------------------------------------------------------------------
// prep_w: transpose weights to [n][k] bf16. Grid 833 blocks x 256 threads.
//   WtV [256][256] = v_w^T ; WtO [256][256] = out_w^T
//   WtD [320][256]: rows 0-143 qd_w^T, 144-215 qs_w^T, 216-287 qw_w^T, 288-319 zero
//   biasD[320] f32: qd_b / 0 / qw_b / 0
// ---------------------------------------------------------------------------
__global__ __launch_bounds__(256) void prep_w(
    const float* __restrict__ v_w, const float* __restrict__ qd_w,
    const float* __restrict__ qs_w, const float* __restrict__ qw_w,
    const float* __restrict__ out_w, const float* __restrict__ qd_b,
    const float* __restrict__ qw_b,
    unsigned short* __restrict__ WtV, unsigned short* __restrict__ WtD,
    unsigned short* __restrict__ WtO, float* __restrict__ biasD)
{
    const int n = blockIdx.x;
    const int k = threadIdx.x;
    if (n < 256) {
        WtV[n * 256 + k] = f2bf(v_w[k * 256 + n]);
    } else if (n < 576) {
        const int nd = n - 256;
        float val = 0.f;
        if (nd < 144)      val = qd_w[k * 144 + nd];
        else if (nd < 216) val = qs_w[k * 72 + (nd - 144)];
        else if (nd < 288) val = qw_w[k * 72 + (nd - 216)];
        WtD[nd * 256 + k] = f2bf(val);
    } else if (n < 832) {
        const int no = n - 576;
        WtO[no * 256 + k] = f2bf(out_w[k * 256 + no]);
    } else {
        for (int i = k; i < 320; i += 256) {
            float bv = 0.f;
            if (i < 144)                 bv = qd_b[i];
            else if (i >= 216 && i < 288) bv = qw_b[i - 216];
            biasD[i] = bv;
        }
    }
}

// ---------------------------------------------------------------------------
// bf16 MFMA GEMM: Y[M][NCOL] = A[M][256] @ Wt[NCOL][256]^T + bias
// Tile 64x64, 4 waves (2x2), full K=256 in LDS (A 32KB + B 32KB).
// LDS rows are 512B; XOR swizzle granule ^= (row&7) keeps ds_read_b128
// conflicts at <=2-way (free). Staged via global_load_lds with
// inverse-swizzled per-lane global source (linear LDS dest).
// ---------------------------------------------------------------------------
template<int NCT, bool BF16OUT>
__global__ __launch_bounds__(256) void gemm_mfma(
    const unsigned short* __restrict__ A,
    const unsigned short* __restrict__ Wt,
    const float* __restrict__ bias,
    void* __restrict__ Yv)
{
    constexpr int NCOL = NCT * 64;
    __shared__ unsigned short As[64 * 256];
    __shared__ unsigned short Bs[64 * 256];

    const int tid  = threadIdx.x;
    const int wid  = tid >> 6;
    const int lane = tid & 63;
    const int row0 = blockIdx.x * 64;
    const int col0 = blockIdx.y * 64;

    const unsigned short* Ab = A  + (size_t)row0 * 256;
    const unsigned short* Bb = Wt + (size_t)col0 * 256;
    const int rl = lane >> 5;     // 0/1 : which of 2 rows per issue
    const int gl = lane & 31;     // 16B-granule within 512B row

    #pragma unroll
    for (int it = 0; it < 8; ++it) {
        const int r   = wid * 16 + it * 2 + rl;
        const int gsw = gl ^ (r & 7);
        GLOAD16(Ab + r * 256 + gsw * 8, &As[(wid * 16 + it * 2) * 256]);
        GLOAD16(Bb + r * 256 + gsw * 8, &Bs[(wid * 16 + it * 2) * 256]);
    }
    asm volatile("s_waitcnt vmcnt(0)" ::: "memory");
    __syncthreads();

    f32x4 acc00 = {0,0,0,0}, acc01 = {0,0,0,0};
    f32x4 acc10 = {0,0,0,0}, acc11 = {0,0,0,0};

    const int wr = (wid >> 1) * 32;   // wave row base in tile
    const int wc = (wid & 1) * 32;    // wave col base in tile
    const int fr = lane & 15;
    const int fg = lane >> 4;         // 0..3 : k-chunk selector

    const int ra0 = wr + fr, ra1 = ra0 + 16;
    const int rb0 = wc + fr, rb1 = rb0 + 16;
    const int sa  = ra0 & 7;          // (ra1&7)==sa, +16 keeps low 3 bits
    const int sb  = rb0 & 7;

    #pragma unroll
    for (int t = 0; t < 8; ++t) {
        const int gran = t * 4 + fg;
        short8 a0 = *(const short8*)&As[ra0 * 256 + (gran ^ sa) * 8];
        short8 a1 = *(const short8*)&As[ra1 * 256 + (gran ^ sa) * 8];
        short8 b0 = *(const short8*)&Bs[rb0 * 256 + (gran ^ sb) * 8];
        short8 b1 = *(const short8*)&Bs[rb1 * 256 + (gran ^ sb) * 8];
        acc00 = __builtin_amdgcn_mfma_f32_16x16x32_bf16(a0, b0, acc00, 0, 0, 0);
        acc01 = __builtin_amdgcn_mfma_f32_16x16x32_bf16(a0, b1, acc01, 0, 0, 0);
        acc10 = __builtin_amdgcn_mfma_f32_16x16x32_bf16(a1, b0, acc10, 0, 0, 0);
        acc11 = __builtin_amdgcn_mfma_f32_16x16x32_bf16(a1, b1, acc11, 0, 0, 0);
    }

    // C/D layout (m89-verified): col = lane&15, row = (lane>>4)*4 + jj
    const int colA = col0 + wc + fr;
    const int colB = colA + 16;
    const float biasA = bias[colA];
    const float biasB = bias[colB];

    #pragma unroll
    for (int jj = 0; jj < 4; ++jj) {
        const int r0a = row0 + wr + fg * 4 + jj;
        const int r1a = r0a + 16;
        float v00 = acc00[jj] + biasA;
        float v01 = acc01[jj] + biasB;
        float v10 = acc10[jj] + biasA;
        float v11 = acc11[jj] + biasB;
        if (BF16OUT) {
            unsigned short* Y = (unsigned short*)Yv;
            Y[(size_t)r0a * NCOL + colA] = f2bf(v00);
            Y[(size_t)r0a * NCOL + colB] = f2bf(v01);
            Y[(size_t)r1a * NCOL + colA] = f2bf(v10);
            Y[(size_t)r1a * NCOL + colB] = f2bf(v11);
        } else {
            float* Y = (float*)Yv;
            Y[(size_t)r0a * NCOL + colA] = v00;
            Y[(size_t)r0a * NCOL + colB] = v01;
            Y[(size_t)r1a * NCOL + colA] = v10;
            Y[(size_t)r1a * NCOL + colB] = v11;
        }
    }
}

// ---------------------------------------------------------------------------
// Sampler v2: block = 4 pixels x 256 threads.
// Phase 1: 288 (pix,g,k) items -> 4 gather offsets + 4 folded weights in LDS.
// Phase 2: thread (p,g,q) gathers bf16x4 channels, 36 loads, 144 FMA.
// ---------------------------------------------------------------------------
__global__ __launch_bounds__(256) void dcn_sample2(
    const unsigned short* __restrict__ vbuf,  // [NPIX][256] bf16, col = g*32+c
    const float* __restrict__ proj,           // [NPIX][320]: qd 0-143, qs 144-215, qw 216-287
    const float* __restrict__ prior,          // [K][2]
    const float* __restrict__ dscale,         // [G]
    unsigned short* __restrict__ mid)         // [NPIX][256] bf16
{
    __shared__ int   offs[288 * 4];
    __shared__ float wts [288 * 4];

    const int tid  = threadIdx.x;
    const int pix0 = blockIdx.x * 4;

    for (int it = tid; it < 288; it += 256) {
        const int p   = it / 72;
        const int rem = it - p * 72;
        const int g   = rem / 9;
        const int k   = rem - g * 9;
        const int pix = pix0 + p;
        const int b   = pix >> 12;
        const int hw  = pix & 4095;
        const int h   = hw >> 6, w = hw & 63;

        const float* row = proj + (size_t)pix * 320;
        const float qdx = row[g * 18 + k * 2 + 0];
        const float qdy = row[g * 18 + k * 2 + 1];
        const float s   = row[144 + g * 9 + k] + dscale[g];
        const float wt  = row[216 + g * 9 + k];
        const float sig6 = 6.0f / (1.0f + __expf(-s));
        const float px = (float)w + (qdx + prior[k * 2 + 0]) * sig6;
        const float py = (float)h + (qdy + prior[k * 2 + 1]) * sig6;

        const float x0f = floorf(px), y0f = floorf(py);
        const int ix = (int)x0f, iy = (int)y0f;
        const float wx1 = px - x0f, wx0 = 1.f - wx1;
        const float wy1 = py - y0f, wy0 = 1.f - wy1;
        const int base_b = b << 12;

        #pragma unroll
        for (int tp = 0; tp < 4; ++tp) {
            const int yy = iy + (tp >> 1), xx = ix + (tp & 1);
            const bool valid = (yy >= 0) & (yy < 64) & (xx >= 0) & (xx < 64);
            const int yc = min(max(yy, 0), 63), xc = min(max(xx, 0), 63);
            const float wgt = wt * ((tp >> 1) ? wy1 : wy0) * ((tp & 1) ? wx1 : wx0);
            offs[it * 4 + tp] = ((base_b + yc * 64 + xc) << 8) + g * 32;
            wts [it * 4 + tp] = valid ? wgt : 0.f;
        }
    }
    __syncthreads();

    const int p = tid >> 6;
    const int g = (tid >> 3) & 7;
    const int q = tid & 7;
    const int c0 = q * 4;
    const int item0 = p * 72 + g * 9;

    float a0 = 0.f, a1 = 0.f, a2 = 0.f, a3 = 0.f;
    #pragma unroll
    for (int k = 0; k < 9; ++k) {
        const int it4 = (item0 + k) * 4;
        const int4   o4 = *(const int4*)&offs[it4];
        const float4 w4 = *(const float4*)&wts[it4];
        {
            const uint2 r = *(const uint2*)(vbuf + o4.x + c0);
            a0 = fmaf(w4.x, __uint_as_float(r.x << 16), a0);
            a1 = fmaf(w4.x, __uint_as_float(r.x & 0xffff0000u), a1);
            a2 = fmaf(w4.x, __uint_as_float(r.y << 16), a2);
            a3 = fmaf(w4.x, __uint_as_float(r.y & 0xffff0000u), a3);
        }
        {
            const uint2 r = *(const uint2*)(vbuf + o4.y + c0);
            a0 = fmaf(w4.y, __uint_as_float(r.x << 16), a0);
            a1 = fmaf(w4.y, __uint_as_float(r.x & 0xffff0000u), a1);
            a2 = fmaf(w4.y, __uint_as_float(r.y << 16), a2);
            a3 = fmaf(w4.y, __uint_as_float(r.y & 0xffff0000u), a3);
        }
        {
            const uint2 r = *(const uint2*)(vbuf + o4.z + c0);
            a0 = fmaf(w4.z, __uint_as_float(r.x << 16), a0);
            a1 = fmaf(w4.z, __uint_as_float(r.x & 0xffff0000u), a1);
            a2 = fmaf(w4.z, __uint_as_float(r.y << 16), a2);
            a3 = fmaf(w4.z, __uint_as_float(r.y & 0xffff0000u), a3);
        }
        {
            const uint2 r = *(const uint2*)(vbuf + o4.w + c0);
            a0 = fmaf(w4.w, __uint_as_float(r.x << 16), a0);
            a1 = fmaf(w4.w, __uint_as_float(r.x & 0xffff0000u), a1);
            a2 = fmaf(w4.w, __uint_as_float(r.y << 16), a2);
            a3 = fmaf(w4.w, __uint_as_float(r.y & 0xffff0000u), a3);
        }
    }

    const int pix = pix0 + p;
    unsigned short* mp = mid + (size_t)pix * 256 + g * 32 + c0;
    const unsigned lo = f2bf(a0) | ((unsigned)f2bf(a1) << 16);
    const unsigned hi = f2bf(a2) | ((unsigned)f2bf(a3) << 16);
    *(uint2*)mp = make_uint2(lo, hi);
}

// ---------------------------------------------------------------------------
extern "C" void kernel_launch(void* const* d_in, const int* in_sizes, int n_in,
                              void* d_out, int out_size, void* d_ws, size_t ws_size,
                              hipStream_t stream)
{
    (void)in_sizes; (void)n_in; (void)out_size; (void)ws_size;

    const float* x      = (const float*)d_in[0];
    const float* v_w    = (const float*)d_in[1];
    const float* v_b    = (const float*)d_in[2];
    const float* qd_w   = (const float*)d_in[3];
    const float* qd_b   = (const float*)d_in[4];
    const float* qs_w   = (const float*)d_in[5];
    const float* qw_w   = (const float*)d_in[6];
    const float* qw_b   = (const float*)d_in[7];
    const float* out_w  = (const float*)d_in[8];
    const float* out_b  = (const float*)d_in[9];
    const float* prior  = (const float*)d_in[10];
    const float* dscale = (const float*)d_in[11];
    float* out = (float*)d_out;

    char* ws = (char*)d_ws;
    unsigned short* xb    = (unsigned short*)(ws);                    // 8 MB
    unsigned short* v_bf  = (unsigned short*)(ws + 8388608);          // 8 MB
    float*          proj  = (float*)(ws + 16777216);                  // 20 MB
    unsigned short* mid   = (unsigned short*)(ws + 37748736);         // 8 MB
    unsigned short* WtV   = (unsigned short*)(ws + 46137344);         // 128 KB
    unsigned short* WtD   = (unsigned short*)(ws + 46268416);         // 160 KB
    unsigned short* WtO   = (unsigned short*)(ws + 46432256);         // 128 KB
    float*          biasD = (float*)(ws + 46563328);                  // 1.25 KB

    prep_x<<<dim3(2048), dim3(256), 0, stream>>>(x, xb);
    prep_w<<<dim3(833), dim3(256), 0, stream>>>(v_w, qd_w, qs_w, qw_w, out_w,
                                                qd_b, qw_b, WtV, WtD, WtO, biasD);

    gemm_mfma<4, true ><<<dim3(256, 4), dim3(256), 0, stream>>>(xb, WtV, v_b, v_bf);
    gemm_mfma<5, false><<<dim3(256, 5), dim3(256), 0, stream>>>(xb, WtD, biasD, proj);

    dcn_sample2<<<dim3(NPIX / 4), dim3(256), 0, stream>>>(v_bf, proj, prior, dscale, mid);

    gemm_mfma<4, false><<<dim3(256, 4), dim3(256), 0, stream>>>(mid, WtO, out_b, out);
}